// Round 5
// baseline (1039.214 us; speedup 1.0000x reference)
//
#include <hip/hip_runtime.h>

typedef unsigned short u16;
typedef unsigned int   u32;
typedef __bf16 bf16x8 __attribute__((ext_vector_type(8)));
typedef float  f32x4  __attribute__((ext_vector_type(4)));
typedef float  f32x2  __attribute__((ext_vector_type(2)));
typedef unsigned short u16x8 __attribute__((ext_vector_type(8)));
typedef unsigned int   u32x2 __attribute__((ext_vector_type(2)));
typedef unsigned int   u32x4 __attribute__((ext_vector_type(4)));

#define PPB 128   // pairs per chunk (8 m-tiles)
#define CPB 5     // chunks per block

__device__ __forceinline__ u16 f2bf(float f){           // prep kernels only
  union { float f; u32 i; } v; v.f = f;
  u32 u = v.i;
  u += 0x7fffu + ((u >> 16) & 1u);
  return (u16)(u >> 16);
}
// native casts -> compiler emits v_cvt_pk_bf16_f32 (RNE)
__device__ __forceinline__ u32 pkbf(float lo, float hi){
  union { __bf16 h[2]; u32 u; } v;
  v.h[0] = (__bf16)lo; v.h[1] = (__bf16)hi;
  return v.u;
}
// inf-safe tanh: x->+inf: t=inf, rcp=0 -> 1; x->-inf: t=0 -> -1. No clamp needed.
__device__ __forceinline__ float tanh_fast(float x){
  float t = __builtin_amdgcn_exp2f(x * 2.885390081777926815f); // e^{2x}
  return __builtin_fmaf(-2.f, __builtin_amdgcn_rcpf(t + 1.f), 1.f);
}
// async global->LDS, 16B/lane; lds base wave-uniform, gp per-lane
__device__ __forceinline__ void gload16(const float* gp, u16* lp){
  __builtin_amdgcn_global_load_lds(
      (const __attribute__((address_space(1))) u32*)gp,
      (__attribute__((address_space(3))) u32*)lp, 16, 0, 0);
}

// ------- transpose+downcast: in f32[R][C] -> out bf16[C][R]; R,C mult of 64
__global__ __launch_bounds__(256) void transpose_cast_k(
    const float* __restrict__ in, u16* __restrict__ out, int R, int C)
{
  __shared__ u16 tile[64][65];
  const int tx = threadIdx.x & 63;
  const int ty = threadIdx.x >> 6;
  const int c0 = blockIdx.x * 64;
  const int r0 = blockIdx.y * 64;
#pragma unroll
  for (int rr = 0; rr < 16; ++rr){
    int r = ty + rr * 4;
    tile[r][tx] = f2bf(in[(size_t)(r0 + r) * C + c0 + tx]);
  }
  __syncthreads();
#pragma unroll
  for (int rr = 0; rr < 16; ++rr){
    int r = ty + rr * 4;
    out[(size_t)(c0 + r) * R + r0 + tx] = tile[tx][r];
  }
}

// ------- W2 f32[256][512] -> w2b bf16[8][512][32]: w2b[kk][n][kl] = W2[kk*32+kl][n]
__global__ __launch_bounds__(256) void w2_block_k(
    const float* __restrict__ in, u16* __restrict__ out)
{
  __shared__ float tile[32][65];
  const int kk = blockIdx.x;
  const int n0 = blockIdx.y * 64;
  const int t  = threadIdx.x;
  {
    int r  = t >> 3;
    int c8 = t & 7;
    const float* src = in + (size_t)(kk*32 + r)*512 + n0 + c8*8;
    f32x4 v0 = *(const f32x4*)src;
    f32x4 v1 = *(const f32x4*)(src + 4);
#pragma unroll
    for (int e = 0; e < 4; ++e){
      tile[r][c8*8 + e]     = v0[e];
      tile[r][c8*8 + 4 + e] = v1[e];
    }
  }
  __syncthreads();
  {
    int c = t >> 2, part = t & 3;
    u16x8 o;
#pragma unroll
    for (int e = 0; e < 8; ++e) o[e] = f2bf(tile[part*8 + e][c]);
    *(u16x8*)(out + ((size_t)kk*512 + n0 + c)*32 + part*8) = o;
  }
}

// ---------------- fused PILayer: register-free async gather via global_load_lds ----
// Per chunk t:  P1: issue global_load_lds raw(t+1) [0 VGPR] | GEMM1(t)->sh_h ; bar
//               P2: GEMM2(t) vs reg W2 -> direct f32x2 stores ; bar (drains vmcnt)
//               R : idx-prefetch(t+2) | rebuild raw->sh_inter (i+j, cvt_pk) ; bar
// raw layout (16B slots, 4 regions iA/iB/jA/jB of 16KB): region r slot (m*8+c):
//   bytes [c*32 + (r&1)*16, +16) of p1[idx_{r>>1}[m]] -> rebuild reads are
//   lane-linear b128 (conflict-free), staging dest is lane-linear (HW requirement).
__global__ __launch_bounds__(1024, 4) void pilayer_kernel(
    const float* __restrict__ p1,     // [N_NODES][64] f32
    const int* __restrict__ pair_i,   // [NP]
    const int* __restrict__ pair_j,   // [NP]
    const float* __restrict__ basis,  // [NP][8] f32
    const u16* __restrict__ w1t,      // [256][64] bf16
    const u16* __restrict__ w2b,      // [8][512][32] bf16 (k-blocked W2^T)
    float* __restrict__ out,          // [NP][64] f32
    int n_pairs)
{
  extern __shared__ __align__(16) u16 smem[];
  u16*   sh_h     = smem;                       // [128][256] swizzled = 65536 B
  u16*   sh_inter = smem + PPB * 256;           // [128][64]  swizzled = 16384 B
  float* raw      = (float*)(sh_inter + PPB*64);// 4 regions x 16384 B  = 65536 B
  u16*   raw_u16  = (u16*)raw;

  const int tid  = threadIdx.x;
  const int blk  = blockIdx.x;
  const int lane = tid & 63;
  const int w    = tid >> 6;     // wave 0..15
  const int m16  = lane & 15;
  const int q    = lane >> 4;    // quad 0..3
  const int sw3  = m16 & 7;
  const int cw   = (w*2 + (q >> 1)) ^ m16;   // sh_h write chunk (4-bit row-XOR)

  // staging role (per wave): region r = w>>2 in {iA,iB,jA,jB}
  const int reg_r    = w >> 2;
  const int reg_half = reg_r & 1;
  const int* pairsrc = (reg_r >> 1) ? pair_j : pair_i;
  const int sm0      = (w & 3) * 32;   // wave's base pair-row for staging
  const int sl_m     = lane >> 3;      // +i*8 + sl_m
  const int sl_c     = lane & 7;

  // ---- Persistent W2 fragments (64 AGPR) + W1 fragments (8 VGPR) ----
  bf16x8 awf[8][2];
#pragma unroll
  for (int kk = 0; kk < 8; ++kk)
#pragma unroll
    for (int nt = 0; nt < 2; ++nt)
      awf[kk][nt] = *(const bf16x8*)(
          w2b + ((size_t)kk*512 + w*32 + nt*16 + m16)*32 + q*8);
  const u16* arow = w1t + (size_t)(w*16 + m16)*64 + q*8;
  bf16x8 af0 = *(const bf16x8*)(arow);
  bf16x8 af1 = *(const bf16x8*)(arow + 32);
  __builtin_amdgcn_sched_barrier(0);

  const int pbase = blk * CPB * PPB;
  const int m_g   = tid >> 3;          // gather/rebuild row 0..127
  const int seg_g = tid & 7;           // 16B chunk 0..7

  // ---- Prologue: idx prefetch for chunk 1 staging, then direct gather chunk 0 ----
  int idxv[4];
  {
    int pn = pbase + PPB;
#pragma unroll
    for (int i = 0; i < 4; ++i){
      int m = pn + sm0 + i*8 + sl_m;
      if (m >= n_pairs) m = n_pairs - 1;
      idxv[i] = pairsrc[m];
    }
  }
  __builtin_amdgcn_sched_barrier(0);
  {
    int p = pbase + m_g;
    if (p >= n_pairs) p = n_pairs - 1;
    const float* si = p1 + (size_t)pair_i[p]*64 + seg_g*8;
    const float* sj = p1 + (size_t)pair_j[p]*64 + seg_g*8;
    f32x4 a0 = ((const f32x4*)si)[0], a1 = ((const f32x4*)si)[1];
    f32x4 b0 = ((const f32x4*)sj)[0], b1 = ((const f32x4*)sj)[1];
    u32x4 o;
    o[0] = pkbf(a0[0]+b0[0], a0[1]+b0[1]);
    o[1] = pkbf(a0[2]+b0[2], a0[3]+b0[3]);
    o[2] = pkbf(a1[0]+b1[0], a1[1]+b1[1]);
    o[3] = pkbf(a1[2]+b1[2], a1[3]+b1[3]);
    *(u32x4*)(sh_inter + m_g*64 + ((seg_g ^ (m_g & 7)) * 8)) = o;
  }
  __syncthreads();

  for (int t = 0; t < CPB; ++t){
    const int pb = pbase + t * PPB;
    const bool pf = (t + 1 < CPB);

    // ---- P1: issue async raw staging for chunk t+1 (zero registers held) ----
    if (pf){
#pragma unroll
      for (int i = 0; i < 4; ++i){
        const float* gp = p1 + (size_t)(u32)idxv[i]*64 + sl_c*8 + reg_half*4;
        u16* lp = raw_u16 + reg_r*8192 + (w & 3)*2048 + i*512;  // u16 units
        gload16(gp, lp);
      }
    }
    __builtin_amdgcn_sched_barrier(0);

    // ---- P1: GEMM1 + tanh -> sh_h ----
    for (int mt1 = 0; mt1 < PPB/16; ++mt1){
      const u16* irow = sh_inter + (size_t)(mt1*16 + m16) * 64;
      bf16x8 b0 = *(const bf16x8*)(irow + ((q ^ sw3) * 8));
      bf16x8 b1 = *(const bf16x8*)(irow + (((q + 4) ^ sw3) * 8));
      f32x4 acc = {0.f, 0.f, 0.f, 0.f};
      acc = __builtin_amdgcn_mfma_f32_16x16x32_bf16(af0, b0, acc, 0, 0, 0);
      acc = __builtin_amdgcn_mfma_f32_16x16x32_bf16(af1, b1, acc, 0, 0, 0);
      u32x2 pk;
      pk[0] = pkbf(tanh_fast(acc[0]), tanh_fast(acc[1]));
      pk[1] = pkbf(tanh_fast(acc[2]), tanh_fast(acc[3]));
      *(u32x2*)(sh_h + (size_t)(mt1*16 + m16)*256 + cw*8 + (q & 1)*4) = pk;
    }
    __syncthreads();

    // ---- P2: GEMM2 vs register W2, fold basis, direct store ----
    {
      int mg0c = pb + m16; if (mg0c >= n_pairs) mg0c = n_pairs - 1;
      f32x4 bb = *(const f32x4*)(basis + (size_t)mg0c*8 + (q & 1)*4);
      for (int mt = 0; mt < PPB/16; ++mt){
        const int row = mt*16 + m16;
        const int mg  = pb + row;
        f32x4 bbn;
        if (mt < 7){
          int mgn = mg + 16; if (mgn >= n_pairs) mgn = n_pairs - 1;
          bbn = *(const f32x4*)(basis + (size_t)mgn*8 + (q & 1)*4);
        }

        const u16* hbase = sh_h + (size_t)row * 256;
        f32x4 acc0 = {0.f, 0.f, 0.f, 0.f};
        f32x4 acc1 = {0.f, 0.f, 0.f, 0.f};

        bf16x8 bh = *(const bf16x8*)(hbase + ((q ^ m16) * 8));   // chunk kk=0
#pragma unroll
        for (int kk = 0; kk < 8; ++kk){
          bf16x8 bhn;
          if (kk < 7) bhn = *(const bf16x8*)(hbase + ((((kk + 1)*4 + q) ^ m16) * 8));
          acc0 = __builtin_amdgcn_mfma_f32_16x16x32_bf16(awf[kk][0], bh, acc0, 0, 0, 0);
          acc1 = __builtin_amdgcn_mfma_f32_16x16x32_bf16(awf[kk][1], bh, acc1, 0, 0, 0);
          bh = bhn;
        }

        // n = w*32 + nt*16 + q*4 + reg; c = w*4 + nt*2 + (q>>1); b = (q&1)*4 + reg
#pragma unroll
        for (int nt = 0; nt < 2; ++nt){
          f32x4 a = (nt == 0) ? acc0 : acc1;
          float s = a[0]*bb[0] + a[1]*bb[1] + a[2]*bb[2] + a[3]*bb[3];
          s += __shfl_xor(s, 16);          // sum b-halves
          float v2 = __shfl_xor(s, 32);    // partner c-channel
          if (q == 0 && mg < n_pairs){
            f32x2 pk = {s, v2};
            *(f32x2*)(out + (size_t)mg*64 + w*4 + nt*2) = pk;
          }
        }
        bb = bbn;
      }
    }
    __syncthreads();   // drains vmcnt -> raw(t+1) complete for all waves

    // ---- R: rebuild raw -> sh_inter (i+j, convert), prefetch idx(t+2) ----
    if (pf){
      if (t + 2 < CPB){
        int pn2 = pb + 2*PPB;
#pragma unroll
        for (int i = 0; i < 4; ++i){
          int m = pn2 + sm0 + i*8 + sl_m;
          if (m >= n_pairs) m = n_pairs - 1;
          idxv[i] = pairsrc[m];
        }
      }
      __builtin_amdgcn_sched_barrier(0);
      f32x4 iA = *(const f32x4*)(raw +         tid*4);
      f32x4 iB = *(const f32x4*)(raw +  4096 + tid*4);
      f32x4 jA = *(const f32x4*)(raw +  8192 + tid*4);
      f32x4 jB = *(const f32x4*)(raw + 12288 + tid*4);
      u32x4 o;
      o[0] = pkbf(iA[0]+jA[0], iA[1]+jA[1]);
      o[1] = pkbf(iA[2]+jA[2], iA[3]+jA[3]);
      o[2] = pkbf(iB[0]+jB[0], iB[1]+jB[1]);
      o[3] = pkbf(iB[2]+jB[2], iB[3]+jB[3]);
      *(u32x4*)(sh_inter + m_g*64 + ((seg_g ^ (m_g & 7)) * 8)) = o;
      __syncthreads();
    }
  }
}

extern "C" void kernel_launch(void* const* d_in, const int* in_sizes, int n_in,
                              void* d_out, int out_size, void* d_ws, size_t ws_size,
                              hipStream_t stream)
{
  const float* p1    = (const float*)d_in[0];
  const int*   pi    = (const int*)d_in[1];
  const int*   pj    = (const int*)d_in[2];
  const float* basis = (const float*)d_in[3];
  const float* W1    = (const float*)d_in[4];  // [64][256] f32
  const float* W2    = (const float*)d_in[5];  // [256][512] f32
  float* out = (float*)d_out;

  u16* w1t = (u16*)d_ws;                   // [256][64]   bf16 = 32 KB
  u16* w2b = w1t + 64 * 256;               // [8][512][32] bf16 = 256 KB

  const int n_pairs = in_sizes[1];
  const int lds_bytes = PPB*256*2 + PPB*64*2 + 65536;   // 65536+16384+65536 = 147456

  static int attr_done = 0;  // attribute is device-global state, not stream work;
  if (!attr_done){           // first (uncaptured) call sets it before capture
    hipFuncSetAttribute((const void*)pilayer_kernel,
                        hipFuncAttributeMaxDynamicSharedMemorySize, lds_bytes);
    attr_done = 1;
  }

  transpose_cast_k<<<dim3(4, 1), 256, 0, stream>>>(W1, w1t, 64, 256);
  w2_block_k<<<dim3(8, 8), 256, 0, stream>>>(W2, w2b);

  const int n_chunks = (n_pairs + PPB - 1) / PPB;
  const int blocks   = (n_chunks + CPB - 1) / CPB;
  pilayer_kernel<<<blocks, 1024, lds_bytes, stream>>>(
      p1, pi, pj, basis, w1t, w2b, out, n_pairs);
}

// Round 6
// 567.879 us; speedup vs baseline: 1.8300x; 1.8300x over previous
//
#include <hip/hip_runtime.h>

typedef unsigned short u16;
typedef unsigned int   u32;
typedef __bf16 bf16x8 __attribute__((ext_vector_type(8)));
typedef _Float16 f16x8 __attribute__((ext_vector_type(8)));
typedef float  f32x4  __attribute__((ext_vector_type(4)));
typedef float  f32x2  __attribute__((ext_vector_type(2)));
typedef unsigned short u16x8 __attribute__((ext_vector_type(8)));
typedef unsigned int   u32x2 __attribute__((ext_vector_type(2)));
typedef unsigned int   u32x4 __attribute__((ext_vector_type(4)));

#define PPB 160   // pairs per block (10 m-tiles)

__device__ __forceinline__ u16 f2bf(float f){           // prep kernels only
  union { float f; u32 i; } v; v.f = f;
  u32 u = v.i;
  u += 0x7fffu + ((u >> 16) & 1u);
  return (u16)(u >> 16);
}
// native casts -> compiler emits v_cvt_pk_bf16_f32 (RNE)
__device__ __forceinline__ u32 pkbf(float lo, float hi){
  union { __bf16 h[2]; u32 u; } v;
  v.h[0] = (__bf16)lo; v.h[1] = (__bf16)hi;
  return v.u;
}
// inf-safe tanh: x->+inf: t=inf, rcp=0 -> 1; x->-inf: t=0 -> -1.
__device__ __forceinline__ float tanh_fast(float x){
  float t = __builtin_amdgcn_exp2f(x * 2.885390081777926815f); // e^{2x}
  return __builtin_fmaf(-2.f, __builtin_amdgcn_rcpf(t + 1.f), 1.f);
}

// ------- p1 f32 -> f16 table (6.4 MB, mostly L2-resident; halves gather traffic)
__global__ __launch_bounds__(256) void p1_to_f16_k(
    const float* __restrict__ in, u16* __restrict__ out, int n8)
{
  int t = blockIdx.x * 256 + threadIdx.x;
  if (t >= n8) return;
  f32x4 v0 = *(const f32x4*)(in + (size_t)t*8);
  f32x4 v1 = *(const f32x4*)(in + (size_t)t*8 + 4);
  union { _Float16 h; u16 u; } c;
  u16x8 o;
#pragma unroll
  for (int e = 0; e < 4; ++e){ c.h = (_Float16)v0[e]; o[e]   = c.u; }
#pragma unroll
  for (int e = 0; e < 4; ++e){ c.h = (_Float16)v1[e]; o[e+4] = c.u; }
  *(u16x8*)(out + (size_t)t*8) = o;
}

// ------- transpose+downcast: in f32[R][C] -> out bf16[C][R]; R,C mult of 64
__global__ __launch_bounds__(256) void transpose_cast_k(
    const float* __restrict__ in, u16* __restrict__ out, int R, int C)
{
  __shared__ u16 tile[64][65];
  const int tx = threadIdx.x & 63;
  const int ty = threadIdx.x >> 6;
  const int c0 = blockIdx.x * 64;
  const int r0 = blockIdx.y * 64;
#pragma unroll
  for (int rr = 0; rr < 16; ++rr){
    int r = ty + rr * 4;
    tile[r][tx] = f2bf(in[(size_t)(r0 + r) * C + c0 + tx]);
  }
  __syncthreads();
#pragma unroll
  for (int rr = 0; rr < 16; ++rr){
    int r = ty + rr * 4;
    out[(size_t)(c0 + r) * R + r0 + tx] = tile[tx][r];
  }
}

// ------- W2 f32[256][512] -> w2b bf16[8][512][32]: w2b[kk][n][kl] = W2[kk*32+kl][n]
__global__ __launch_bounds__(256) void w2_block_k(
    const float* __restrict__ in, u16* __restrict__ out)
{
  __shared__ float tile[32][65];
  const int kk = blockIdx.x;
  const int n0 = blockIdx.y * 64;
  const int t  = threadIdx.x;
  {
    int r  = t >> 3;
    int c8 = t & 7;
    const float* src = in + (size_t)(kk*32 + r)*512 + n0 + c8*8;
    f32x4 v0 = *(const f32x4*)src;
    f32x4 v1 = *(const f32x4*)(src + 4);
#pragma unroll
    for (int e = 0; e < 4; ++e){
      tile[r][c8*8 + e]     = v0[e];
      tile[r][c8*8 + 4 + e] = v1[e];
    }
  }
  __syncthreads();
  {
    int c = t >> 2, part = t & 3;
    u16x8 o;
#pragma unroll
    for (int e = 0; e < 8; ++e) o[e] = f2bf(tile[part*8 + e][c]);
    *(u16x8*)(out + ((size_t)kk*512 + n0 + c)*32 + part*8) = o;
  }
}

// ---------------- fused PILayer kernel, 160 pairs / 1024 threads ----------------
// R1-proven 3-phase structure (no prefetch regs, no LDS-DMA — those spill at the
// 1024-thread 128-reg/wave cap). Gather reads the f16 p1 table (half bytes, half
// transactions, ~L2-resident) when available.
// P0: inter = bf16(p1h[i]+p1h[j]) -> sh_inter (3-bit chunk swizzle)
// P1: h = bf16(tanh(inter @ W1)) -> sh_h (4-bit chunk swizzle, conflicts 9x down)
// P2: per m-tile: h @ W2 (reg-resident, fp32 acc), fold basis, direct f32x2 store
__global__ __launch_bounds__(1024, 4) void pilayer_kernel(
    const float* __restrict__ p1,     // [N_NODES][64] f32
    const u16* __restrict__ p1h,      // [N_NODES][64] f16 (may be null)
    const int* __restrict__ pair_i,   // [NP]
    const int* __restrict__ pair_j,   // [NP]
    const float* __restrict__ basis,  // [NP][8] f32
    const u16* __restrict__ w1t,      // [256][64] bf16
    const u16* __restrict__ w2b,      // [8][512][32] bf16 (k-blocked W2^T)
    float* __restrict__ out,          // [NP][64] f32
    int n_pairs)
{
  extern __shared__ __align__(16) u16 smem[];
  u16* sh_h     = smem;              // [160][256] swizzled = 81920 B
  u16* sh_inter = smem + PPB * 256;  // [160][64]  swizzled = 20480 B

  const int tid  = threadIdx.x;
  const int blk  = blockIdx.x;
  const int lane = tid & 63;
  const int w    = tid >> 6;     // wave 0..15
  const int m16  = lane & 15;
  const int q    = lane >> 4;    // quad 0..3
  const int sw3  = m16 & 7;      // sh_inter chunk swizzle bits
  const int cw   = (w*2 + (q >> 1)) ^ m16;   // sh_h write chunk (4-bit row-XOR)

  // ---- Persistent W2 fragments (64 regs) + W1 fragments (8 regs) ----
  bf16x8 awf[8][2];
#pragma unroll
  for (int kk = 0; kk < 8; ++kk)
#pragma unroll
    for (int nt = 0; nt < 2; ++nt)
      awf[kk][nt] = *(const bf16x8*)(
          w2b + ((size_t)kk*512 + w*32 + nt*16 + m16)*32 + q*8);
  const u16* arow = w1t + (size_t)(w*16 + m16)*64 + q*8;
  bf16x8 af0 = *(const bf16x8*)(arow);
  bf16x8 af1 = *(const bf16x8*)(arow + 32);
  __builtin_amdgcn_sched_barrier(0);   // keep these loads issued up-front

  // ---- P0: gather inter = bf16(p1[i] + p1[j]) into LDS ----
  if (p1h != nullptr){
    // f16 table path: 1280 units of one 16B i-seg + one 16B j-seg
    for (int u = tid; u < PPB * 8; u += 1024){
      int m   = u >> 3;            // pair row 0..159
      int seg = u & 7;             // 16B chunk (8 f16)
      int p   = blk * PPB + m;
      if (p >= n_pairs) p = n_pairs - 1;
      union { u16x8 u; f16x8 h; } vi, vj;
      vi.u = *(const u16x8*)(p1h + (size_t)pair_i[p]*64 + seg*8);
      vj.u = *(const u16x8*)(p1h + (size_t)pair_j[p]*64 + seg*8);
      u32x4 o;
#pragma unroll
      for (int e = 0; e < 4; ++e)
        o[e] = pkbf((float)vi.h[2*e]   + (float)vj.h[2*e],
                    (float)vi.h[2*e+1] + (float)vj.h[2*e+1]);
      *(u32x4*)(sh_inter + m*64 + ((seg ^ (m & 7)) * 8)) = o;
    }
  } else {
    // fallback f32 path (workspace too small for the table)
    for (int u = tid; u < PPB * 8; u += 1024){
      int m   = u >> 3;
      int seg = u & 7;             // 8-float segment
      int p   = blk * PPB + m;
      if (p >= n_pairs) p = n_pairs - 1;
      const f32x4* pi = (const f32x4*)(p1 + (size_t)pair_i[p]*64 + seg*8);
      const f32x4* pj = (const f32x4*)(p1 + (size_t)pair_j[p]*64 + seg*8);
      f32x4 a0 = pi[0], a1 = pi[1];
      f32x4 b0 = pj[0], b1 = pj[1];
      u32x4 o;
#pragma unroll
      for (int e = 0; e < 2; ++e){
        o[e]   = pkbf(a0[2*e] + b0[2*e], a0[2*e+1] + b0[2*e+1]);
        o[e+2] = pkbf(a1[2*e] + b1[2*e], a1[2*e+1] + b1[2*e+1]);
      }
      *(u32x4*)(sh_inter + m*64 + ((seg ^ (m & 7)) * 8)) = o;
    }
  }
  __syncthreads();

  // ---- P1: h = bf16(tanh(inter @ W1)) -> sh_h ----
  for (int mt1 = 0; mt1 < PPB/16; ++mt1){
    const u16* irow = sh_inter + (size_t)(mt1*16 + m16) * 64;
    bf16x8 b0 = *(const bf16x8*)(irow + ((q ^ sw3) * 8));
    bf16x8 b1 = *(const bf16x8*)(irow + (((q + 4) ^ sw3) * 8));
    f32x4 acc = {0.f, 0.f, 0.f, 0.f};
    acc = __builtin_amdgcn_mfma_f32_16x16x32_bf16(af0, b0, acc, 0, 0, 0);
    acc = __builtin_amdgcn_mfma_f32_16x16x32_bf16(af1, b1, acc, 0, 0, 0);
    u32x2 pk;
    pk[0] = pkbf(tanh_fast(acc[0]), tanh_fast(acc[1]));
    pk[1] = pkbf(tanh_fast(acc[2]), tanh_fast(acc[3]));
    *(u32x2*)(sh_h + (size_t)(mt1*16 + m16)*256 + cw*8 + (q & 1)*4) = pk;
  }
  __syncthreads();

  // ---- P2: per m-tile GEMM2 against register-resident W2, fold basis ----
  for (int mt = 0; mt < PPB/16; ++mt){
    const int row = mt*16 + m16;
    const int mg  = blk * PPB + row;
    const int mgc = (mg < n_pairs) ? mg : (n_pairs - 1);
    f32x4 bb = *(const f32x4*)(basis + (size_t)mgc*8 + (q & 1)*4);

    const u16* hbase = sh_h + (size_t)row * 256;
    f32x4 acc0 = {0.f, 0.f, 0.f, 0.f};
    f32x4 acc1 = {0.f, 0.f, 0.f, 0.f};

    bf16x8 bh = *(const bf16x8*)(hbase + ((q ^ m16) * 8));   // chunk kk=0
#pragma unroll
    for (int kk = 0; kk < 8; ++kk){
      bf16x8 bhn;
      if (kk < 7) bhn = *(const bf16x8*)(hbase + ((((kk + 1)*4 + q) ^ m16) * 8));
      acc0 = __builtin_amdgcn_mfma_f32_16x16x32_bf16(awf[kk][0], bh, acc0, 0, 0, 0);
      acc1 = __builtin_amdgcn_mfma_f32_16x16x32_bf16(awf[kk][1], bh, acc1, 0, 0, 0);
      bh = bhn;
    }

    // n = w*32 + nt*16 + q*4 + reg; c = w*4 + nt*2 + (q>>1); b = (q&1)*4 + reg
#pragma unroll
    for (int nt = 0; nt < 2; ++nt){
      f32x4 a = (nt == 0) ? acc0 : acc1;
      float s = a[0]*bb[0] + a[1]*bb[1] + a[2]*bb[2] + a[3]*bb[3];
      s += __shfl_xor(s, 16);          // sum b-halves (q0+q1 / q2+q3)
      float v2 = __shfl_xor(s, 32);    // partner c-channel
      if (q == 0 && mg < n_pairs){
        f32x2 pk = {s, v2};
        *(f32x2*)(out + (size_t)mg*64 + w*4 + nt*2) = pk;
      }
    }
  }
}

extern "C" void kernel_launch(void* const* d_in, const int* in_sizes, int n_in,
                              void* d_out, int out_size, void* d_ws, size_t ws_size,
                              hipStream_t stream)
{
  const float* p1    = (const float*)d_in[0];
  const int*   pi    = (const int*)d_in[1];
  const int*   pj    = (const int*)d_in[2];
  const float* basis = (const float*)d_in[3];
  const float* W1    = (const float*)d_in[4];  // [64][256] f32
  const float* W2    = (const float*)d_in[5];  // [256][512] f32
  float* out = (float*)d_out;

  const int n_pairs = in_sizes[1];
  const int n_nodes = in_sizes[0] / 64;        // p1 floats / 64

  u16* w1t = (u16*)d_ws;                       // [256][64]    bf16 = 32 KB
  u16* w2b = w1t + 64 * 256;                   // [8][512][32] bf16 = 256 KB
  u16* p1h = w2b + 8 * 512 * 32;               // [n_nodes][64] f16 = 6.4 MB
  const size_t need = (size_t)(64*256 + 8*512*32 + n_nodes*64) * sizeof(u16);
  const bool use_h = (ws_size >= need);

  const int lds_bytes = (PPB * 256 + PPB * 64) * (int)sizeof(u16);  // 102400

  static int attr_done = 0;  // attribute is device-global state, not stream work;
  if (!attr_done){           // first (uncaptured) call sets it before capture
    hipFuncSetAttribute((const void*)pilayer_kernel,
                        hipFuncAttributeMaxDynamicSharedMemorySize, lds_bytes);
    attr_done = 1;
  }

  transpose_cast_k<<<dim3(4, 1), 256, 0, stream>>>(W1, w1t, 64, 256);
  w2_block_k<<<dim3(8, 8), 256, 0, stream>>>(W2, w2b);
  if (use_h){
    const int n8 = n_nodes * 8;                // 16B units
    p1_to_f16_k<<<(n8 + 255)/256, 256, 0, stream>>>(p1, p1h, n8);
  }

  const int blocks = (n_pairs + PPB - 1) / PPB;
  pilayer_kernel<<<blocks, 1024, lds_bytes, stream>>>(
      p1, use_h ? p1h : nullptr, pi, pj, basis, w1t, w2b, out, n_pairs);
}